// Round 9
// baseline (143.342 us; speedup 1.0000x reference)
//
#include <hip/hip_runtime.h>
#include <math.h>

typedef __attribute__((ext_vector_type(8))) short bf16x8;
typedef __attribute__((ext_vector_type(4))) float f32x4;

#define W1S_OFF 0
#define W2S_OFF 262144
#define MZ_OFF  393216          // byte 786432: motifs_z as FP32, [p=m*64+c][16] (12 used, 4 pad)

__device__ __forceinline__ ushort f2bf(float x){
    union{float f; unsigned u;} v; v.f = x;
    unsigned r = v.u + 0x7fffu + ((v.u >> 16) & 1u);
    return (ushort)(r >> 16);
}

// gelu(v) ~= v * sigmoid(1.5957691*v + 0.0713548*v^3)  (tanh-form GELU, |err|<4e-4)
__device__ __forceinline__ float fast_gelu(float v){
    float vv = v * v;
    float a  = fmaf(-0.1029458859f, vv, -2.3022240867f);
    float ex = __builtin_amdgcn_exp2f(a * v);
    return v * __builtin_amdgcn_rcpf(1.0f + ex);
}

// Pack W1 (512x512) and W2 (512x256) into bf16 MFMA-B-fragment order.
// B-frag layout: ws[((tn_g*16 + tk)*64 + lane)*8 + j] = W[k][n],
//   k = tk*32 + (lane>>4)*8 + j,  n = tn_g*16 + (lane&15).
__global__ __launch_bounds__(256) void prep_kernel(
    const float* __restrict__ W1, const float* __restrict__ W2,
    const float* __restrict__ motifs, ushort* __restrict__ ws)
{
    int idx = blockIdx.x * 256 + threadIdx.x;
    if (idx < 262144) {                        // W1: idx = k*512 + n
        int k = idx >> 9, n = idx & 511;
        int tk = k >> 5, j = k & 7, hig = (k >> 3) & 3;
        int tn = n >> 4, lo = n & 15;
        int lane = hig * 16 + lo;
        ws[W1S_OFF + (((tn*16 + tk)*64 + lane)*8 + j)] = f2bf(W1[idx]);
    } else if (idx < 393216) {                 // W2: i = k*256 + n
        int i = idx - 262144;
        int k = i >> 8, n = i & 255;
        int tk = k >> 5, j = k & 7, hig = (k >> 3) & 3;
        int tn = n >> 4, lo = n & 15;
        int lane = hig * 16 + lo;
        ws[W2S_OFF + (((tn*16 + tk)*64 + lane)*8 + j)] = f2bf(W2[i]);
    } else if (idx < 393216 + 512) {
        int p = idx - 393216;                  // p = m*64 + c
        const float* mp = motifs + p*12;
        float v[12]; float sm = 0.f;
        #pragma unroll
        for (int l = 0; l < 12; ++l){ v[l] = mp[l]; sm += v[l]; }
        float mean = sm * (1.f/12.f), sq = 0.f;
        #pragma unroll
        for (int l = 0; l < 12; ++l){ float d = v[l]-mean; sq = fmaf(d,d,sq); }
        float inv = 1.f / (sqrtf(sq*(1.f/12.f)) + 1e-8f);
        float* mzf = (float*)(ws + MZ_OFF);
        #pragma unroll
        for (int l = 0; l < 12; ++l) mzf[p*16 + l] = (v[l]-mean)*inv;
        #pragma unroll
        for (int l = 12; l < 16; ++l) mzf[p*16 + l] = 0.f;
    }
}

// Swizzled byte offset into the [32][512] bf16 LDS tile (conflict-free b128 A-frag reads)
#define SWZ(r, k) (((((r) << 9) + (k)) << 1) ^ (((r) & 7) << 4))

// One block = 32 rows, 512 threads (8 waves), 3 blocks/CU via launch_bounds(512,6).
__global__ __launch_bounds__(512, 6) void fused_kernel(
    const float* __restrict__ x, const ushort* __restrict__ ws,
    const float* __restrict__ b1, const float* __restrict__ gamma,
    const float* __restrict__ beta, const float* __restrict__ b2,
    float* __restrict__ out)
{
    __shared__ __align__(16) ushort fl[32*512];   // 32 KB: flat -> hn -> fp32 out tile
    __shared__ float part[32][8][2];              // per-wave LN partials
    __shared__ float mu_s[32];
    __shared__ float rs_s[32];

    const int t  = threadIdx.x;
    const int g0 = blockIdx.x * 32;               // global row base (row = bi*4096+s)

    const int w    = t >> 6;          // wave 0..7
    const int lane = t & 63;
    const int hi   = lane >> 4;
    const int lo   = lane & 15;
    const int n0   = w * 64;

    // ---------------- Phase A: per-row window z-norm + motif dots (fp32 mz) ----------------
    {
        const int c  = t & 63;
        const int rg = t >> 6;                    // rows rg*4 .. rg*4+3
        const float* mzf = (const float*)(ws + MZ_OFF);
        const int sb0 = (g0 & 4095) + rg*4;
        const size_t xbase = (size_t)(g0 & ~4095) * 64 + c;

        #pragma unroll 1
        for (int i = 0; i < 4; ++i) {
            const int sb = sb0 + i;
            float wv[12];
            #pragma unroll
            for (int l = 0; l < 12; ++l) {
                int sw = sb - 11 + l; sw = sw < 0 ? 0 : sw;
                wv[l] = x[xbase + (size_t)sw * 64];
            }
            float sm = 0.f;
            #pragma unroll
            for (int l = 0; l < 12; ++l) sm += wv[l];
            float mean = sm * (1.f/12.f), sq = 0.f;
            #pragma unroll
            for (int l = 0; l < 12; ++l){ float d = wv[l]-mean; sq = fmaf(d,d,sq); }
            float sd  = sqrtf(sq * (1.f/12.f)) + 1e-8f;
            float inv = 1.f / (12.f * sd);        // fold 1/L sim scale into the window norm
            #pragma unroll
            for (int l = 0; l < 12; ++l) wv[l] = (wv[l]-mean)*inv;

            const int r = rg*4 + i;
            char* sbase = (char*)fl + ((r*1024 + 2*c) ^ ((r & 7) << 4));
            #pragma unroll
            for (int m = 0; m < 8; ++m) {
                const float4* mp = (const float4*)(mzf + (m*64 + c)*16);
                float4 m0 = mp[0], m1 = mp[1], m2 = mp[2];
                float dot = wv[0] * m0.x;
                dot = fmaf(wv[1],  m0.y, dot);
                dot = fmaf(wv[2],  m0.z, dot);
                dot = fmaf(wv[3],  m0.w, dot);
                dot = fmaf(wv[4],  m1.x, dot);
                dot = fmaf(wv[5],  m1.y, dot);
                dot = fmaf(wv[6],  m1.z, dot);
                dot = fmaf(wv[7],  m1.w, dot);
                dot = fmaf(wv[8],  m2.x, dot);
                dot = fmaf(wv[9],  m2.y, dot);
                dot = fmaf(wv[10], m2.z, dot);
                dot = fmaf(wv[11], m2.w, dot);
                float rv  = fmaxf(dot, 0.f);
                float rv2 = rv * rv;
                *(ushort*)(sbase + m*128) = f2bf(rv2*rv2);   // m*128 commutes with the XOR
            }
        }
    }

    // ---------------- GEMM1: [32x512]x[512x512], 2-named-buffer prefetch ----------------
    const ushort* ws1 = ws + W1S_OFF;
    bf16x8 p0[4], p1[4];
    #pragma unroll
    for (int tn = 0; tn < 4; ++tn) {
        p0[tn] = *(const bf16x8*)(ws1 + (size_t)((w*4 + tn)*16 + 0)*512 + lane*8);
        p1[tn] = *(const bf16x8*)(ws1 + (size_t)((w*4 + tn)*16 + 1)*512 + lane*8);
    }

    __syncthreads();

    f32x4 acc[2][4];
    #pragma unroll
    for (int mt = 0; mt < 2; ++mt)
        #pragma unroll
        for (int tn = 0; tn < 4; ++tn)
            acc[mt][tn] = (f32x4){0.f,0.f,0.f,0.f};

    #pragma unroll
    for (int th = 0; th < 8; ++th) {
        {
            const int tk = 2*th;
            bf16x8 a0[2];
            #pragma unroll
            for (int mt = 0; mt < 2; ++mt)
                a0[mt] = *(const bf16x8*)((char*)fl + SWZ(mt*16 + lo, tk*32 + hi*8));
            #pragma unroll
            for (int tn = 0; tn < 4; ++tn)
                #pragma unroll
                for (int mt = 0; mt < 2; ++mt)
                    acc[mt][tn] = __builtin_amdgcn_mfma_f32_16x16x32_bf16(a0[mt], p0[tn], acc[mt][tn], 0, 0, 0);
            if (th < 7) {
                #pragma unroll
                for (int tn = 0; tn < 4; ++tn)
                    p0[tn] = *(const bf16x8*)(ws1 + (size_t)((w*4 + tn)*16 + tk + 2)*512 + lane*8);
            }
        }
        {
            const int tk = 2*th + 1;
            bf16x8 a1[2];
            #pragma unroll
            for (int mt = 0; mt < 2; ++mt)
                a1[mt] = *(const bf16x8*)((char*)fl + SWZ(mt*16 + lo, tk*32 + hi*8));
            #pragma unroll
            for (int tn = 0; tn < 4; ++tn)
                #pragma unroll
                for (int mt = 0; mt < 2; ++mt)
                    acc[mt][tn] = __builtin_amdgcn_mfma_f32_16x16x32_bf16(a1[mt], p1[tn], acc[mt][tn], 0, 0, 0);
            if (th < 7) {
                #pragma unroll
                for (int tn = 0; tn < 4; ++tn)
                    p1[tn] = *(const bf16x8*)(ws1 + (size_t)((w*4 + tn)*16 + tk + 2)*512 + lane*8);
            }
        }
    }

    // ---------------- bias + fast gelu (in regs) ----------------
    {
        float b1v[4];
        #pragma unroll
        for (int tn = 0; tn < 4; ++tn) b1v[tn] = b1[n0 + tn*16 + lo];
        #pragma unroll
        for (int mt = 0; mt < 2; ++mt)
            #pragma unroll
            for (int tn = 0; tn < 4; ++tn)
                #pragma unroll
                for (int e = 0; e < 4; ++e)
                    acc[mt][tn][e] = fast_gelu(acc[mt][tn][e] + b1v[tn]);
    }

    // ---------------- LayerNorm: partials -> stats -> normalize -> hn bf16 LDS ----------------
    #pragma unroll
    for (int mt = 0; mt < 2; ++mt)
        #pragma unroll
        for (int e = 0; e < 4; ++e) {
            float s1 = 0.f, s2 = 0.f;
            #pragma unroll
            for (int tn = 0; tn < 4; ++tn) {
                float g = acc[mt][tn][e];
                s1 += g; s2 = fmaf(g, g, s2);
            }
            #pragma unroll
            for (int o = 1; o < 16; o <<= 1) {
                s1 += __shfl_xor(s1, o);
                s2 += __shfl_xor(s2, o);
            }
            if (lo == 0) {
                int row = mt*16 + hi*4 + e;
                part[row][w][0] = s1;
                part[row][w][1] = s2;
            }
        }
    __syncthreads();
    if (t < 32) {
        float s1 = 0.f, s2 = 0.f;
        #pragma unroll
        for (int ww = 0; ww < 8; ++ww) { s1 += part[t][ww][0]; s2 += part[t][ww][1]; }
        float mu  = s1 * (1.f/512.f);
        float var = s2 * (1.f/512.f) - mu*mu;
        mu_s[t] = mu;
        rs_s[t] = rsqrtf(var + 1e-5f);
    }
    __syncthreads();
    {
        float gv[4], bv[4];
        #pragma unroll
        for (int tn = 0; tn < 4; ++tn) {
            gv[tn] = gamma[n0 + tn*16 + lo];
            bv[tn] = beta[n0 + tn*16 + lo];
        }
        #pragma unroll
        for (int mt = 0; mt < 2; ++mt)
            #pragma unroll
            for (int e = 0; e < 4; ++e) {
                int row = mt*16 + hi*4 + e;
                float mu = mu_s[row], rs = rs_s[row];
                #pragma unroll
                for (int tn = 0; tn < 4; ++tn) {
                    float hn = (acc[mt][tn][e] - mu) * rs * gv[tn] + bv[tn];
                    int col = n0 + tn*16 + lo;
                    *(ushort*)((char*)fl + SWZ(row, col)) = f2bf(hn);
                }
            }
    }

    // ---------------- GEMM2: [32x512]x[512x256], 2-named-buffer prefetch ----------------
    const ushort* ws2 = ws + W2S_OFF;
    bf16x8 q0[2], q1[2];
    #pragma unroll
    for (int tn = 0; tn < 2; ++tn) {
        q0[tn] = *(const bf16x8*)(ws2 + (size_t)((w*2 + tn)*16 + 0)*512 + lane*8);
        q1[tn] = *(const bf16x8*)(ws2 + (size_t)((w*2 + tn)*16 + 1)*512 + lane*8);
    }

    __syncthreads();

    f32x4 acc2[2][2];
    #pragma unroll
    for (int mt = 0; mt < 2; ++mt)
        #pragma unroll
        for (int tn = 0; tn < 2; ++tn)
            acc2[mt][tn] = (f32x4){0.f,0.f,0.f,0.f};

    #pragma unroll
    for (int th = 0; th < 8; ++th) {
        {
            const int tk = 2*th;
            bf16x8 a0[2];
            #pragma unroll
            for (int mt = 0; mt < 2; ++mt)
                a0[mt] = *(const bf16x8*)((char*)fl + SWZ(mt*16 + lo, tk*32 + hi*8));
            #pragma unroll
            for (int tn = 0; tn < 2; ++tn)
                #pragma unroll
                for (int mt = 0; mt < 2; ++mt)
                    acc2[mt][tn] = __builtin_amdgcn_mfma_f32_16x16x32_bf16(a0[mt], q0[tn], acc2[mt][tn], 0, 0, 0);
            if (th < 7) {
                #pragma unroll
                for (int tn = 0; tn < 2; ++tn)
                    q0[tn] = *(const bf16x8*)(ws2 + (size_t)((w*2 + tn)*16 + tk + 2)*512 + lane*8);
            }
        }
        {
            const int tk = 2*th + 1;
            bf16x8 a1[2];
            #pragma unroll
            for (int mt = 0; mt < 2; ++mt)
                a1[mt] = *(const bf16x8*)((char*)fl + SWZ(mt*16 + lo, tk*32 + hi*8));
            #pragma unroll
            for (int tn = 0; tn < 2; ++tn)
                #pragma unroll
                for (int mt = 0; mt < 2; ++mt)
                    acc2[mt][tn] = __builtin_amdgcn_mfma_f32_16x16x32_bf16(a1[mt], q1[tn], acc2[mt][tn], 0, 0, 0);
            if (th < 7) {
                #pragma unroll
                for (int tn = 0; tn < 2; ++tn)
                    q1[tn] = *(const bf16x8*)(ws2 + (size_t)((w*2 + tn)*16 + tk + 2)*512 + lane*8);
            }
        }
    }

    // ---------------- + b2 -> swizzled fp32 LDS tile -> full-line stores ----------------
    __syncthreads();                              // all GEMM2 LDS reads retired
    {
        float* fl32 = (float*)fl;                 // [32][256] fp32, col4-XOR swizzled
        const int n2 = w * 32;
        float b2v[2];
        #pragma unroll
        for (int tn = 0; tn < 2; ++tn) b2v[tn] = b2[n2 + tn*16 + lo];
        #pragma unroll
        for (int mt = 0; mt < 2; ++mt)
            #pragma unroll
            for (int tn = 0; tn < 2; ++tn) {
                int col = n2 + tn*16 + lo;
                int c4 = col >> 2, ce = col & 3;
                #pragma unroll
                for (int e = 0; e < 4; ++e) {
                    int row = mt*16 + hi*4 + e;
                    fl32[row*256 + (((c4 ^ (row & 7)) << 2) | ce)] = acc2[mt][tn][e] + b2v[tn];
                }
            }
    }
    __syncthreads();
    {
        const float* fl32 = (const float*)fl;
        float4* dst = (float4*)out;
        const int row = t >> 4;                   // 0..31
        const int sg  = t & 15;                   // 0..15
        #pragma unroll
        for (int it = 0; it < 4; ++it) {
            int c4 = sg + it*16;
            float4 v = *(const float4*)&fl32[row*256 + ((c4 ^ (row & 7)) << 2)];
            dst[(size_t)(g0 + row)*64 + c4] = v;
        }
    }
}

extern "C" void kernel_launch(void* const* d_in, const int* in_sizes, int n_in,
                              void* d_out, int out_size, void* d_ws, size_t ws_size,
                              hipStream_t stream) {
    const float* x      = (const float*)d_in[0];
    const float* motifs = (const float*)d_in[1];
    const float* W1     = (const float*)d_in[2];
    const float* b1     = (const float*)d_in[3];
    const float* gamma  = (const float*)d_in[4];
    const float* beta   = (const float*)d_in[5];
    const float* W2     = (const float*)d_in[6];
    const float* b2     = (const float*)d_in[7];
    float* out = (float*)d_out;
    ushort* ws = (ushort*)d_ws;

    prep_kernel<<<(393216 + 512 + 255) / 256, 256, 0, stream>>>(W1, W2, motifs, ws);
    fused_kernel<<<1024, 512, 0, stream>>>(x, ws, b1, gamma, beta, b2, out);
}

// Round 10
// 66.538 us; speedup vs baseline: 2.1543x; 2.1543x over previous
//
#include <hip/hip_runtime.h>
#include <math.h>

typedef __attribute__((ext_vector_type(8))) short bf16x8;
typedef __attribute__((ext_vector_type(4))) float f32x4;

#define W1S_OFF 0
#define W2S_OFF 262144
#define MZ_OFF  393216          // byte 786432: motifs_z as FP32, [p=m*64+c][16] (12 used, 4 pad)

__device__ __forceinline__ ushort f2bf(float x){
    union{float f; unsigned u;} v; v.f = x;
    unsigned r = v.u + 0x7fffu + ((v.u >> 16) & 1u);
    return (ushort)(r >> 16);
}

// gelu(v) ~= v * sigmoid(1.5957691*v + 0.0713548*v^3)  (tanh-form GELU, |err|<4e-4)
__device__ __forceinline__ float fast_gelu(float v){
    float vv = v * v;
    float a  = fmaf(-0.1029458859f, vv, -2.3022240867f);
    float ex = __builtin_amdgcn_exp2f(a * v);
    return v * __builtin_amdgcn_rcpf(1.0f + ex);
}

// Pack W1 (512x512) and W2 (512x256) into bf16 MFMA-B-fragment order.
// B-frag layout: ws[((tn_g*16 + tk)*64 + lane)*8 + j] = W[k][n],
//   k = tk*32 + (lane>>4)*8 + j,  n = tn_g*16 + (lane&15).
__global__ __launch_bounds__(256) void prep_kernel(
    const float* __restrict__ W1, const float* __restrict__ W2,
    const float* __restrict__ motifs, ushort* __restrict__ ws)
{
    int idx = blockIdx.x * 256 + threadIdx.x;
    if (idx < 262144) {                        // W1: idx = k*512 + n
        int k = idx >> 9, n = idx & 511;
        int tk = k >> 5, j = k & 7, hig = (k >> 3) & 3;
        int tn = n >> 4, lo = n & 15;
        int lane = hig * 16 + lo;
        ws[W1S_OFF + (((tn*16 + tk)*64 + lane)*8 + j)] = f2bf(W1[idx]);
    } else if (idx < 393216) {                 // W2: i = k*256 + n
        int i = idx - 262144;
        int k = i >> 8, n = i & 255;
        int tk = k >> 5, j = k & 7, hig = (k >> 3) & 3;
        int tn = n >> 4, lo = n & 15;
        int lane = hig * 16 + lo;
        ws[W2S_OFF + (((tn*16 + tk)*64 + lane)*8 + j)] = f2bf(W2[i]);
    } else if (idx < 393216 + 512) {
        int p = idx - 393216;                  // p = m*64 + c
        const float* mp = motifs + p*12;
        float v[12]; float sm = 0.f;
        #pragma unroll
        for (int l = 0; l < 12; ++l){ v[l] = mp[l]; sm += v[l]; }
        float mean = sm * (1.f/12.f), sq = 0.f;
        #pragma unroll
        for (int l = 0; l < 12; ++l){ float d = v[l]-mean; sq = fmaf(d,d,sq); }
        float inv = 1.f / (sqrtf(sq*(1.f/12.f)) + 1e-8f);
        float* mzf = (float*)(ws + MZ_OFF);
        #pragma unroll
        for (int l = 0; l < 12; ++l) mzf[p*16 + l] = (v[l]-mean)*inv;
        #pragma unroll
        for (int l = 12; l < 16; ++l) mzf[p*16 + l] = 0.f;
    }
}

// Swizzled byte offset into the [32][512] bf16 LDS tile (conflict-free b128 A-frag reads)
#define SWZ(r, k) (((((r) << 9) + (k)) << 1) ^ (((r) & 7) << 4))

// One block = 32 rows, 512 threads (8 waves), 2 blocks/CU. (512,4) is the proven
// no-spill point: 64 arch VGPR + 48 AGPR acc = 112 < 128-reg budget. (512,6) spilled (r9).
__global__ __launch_bounds__(512, 4) void fused_kernel(
    const float* __restrict__ x, const ushort* __restrict__ ws,
    const float* __restrict__ b1, const float* __restrict__ gamma,
    const float* __restrict__ beta, const float* __restrict__ b2,
    float* __restrict__ out)
{
    __shared__ __align__(16) ushort fl[32*512];   // 32 KB: flat -> hn -> fp32 out tile
    __shared__ float part[32][8][2];              // per-wave LN partials
    __shared__ float mu_s[32];
    __shared__ float rs_s[32];

    const int t  = threadIdx.x;
    const int g0 = blockIdx.x * 32;               // global row base (row = bi*4096+s)

    const int w    = t >> 6;          // wave 0..7
    const int lane = t & 63;
    const int hi   = lane >> 4;
    const int lo   = lane & 15;
    const int n0   = w * 64;

    // ---------------- Phase A: per-row window z-norm + motif dots (fp32 mz) ----------------
    {
        const int c  = t & 63;
        const int rg = t >> 6;                    // rows rg*4 .. rg*4+3
        const float* mzf = (const float*)(ws + MZ_OFF);
        const int sb0 = (g0 & 4095) + rg*4;
        const size_t xbase = (size_t)(g0 & ~4095) * 64 + c;

        #pragma unroll 1
        for (int i = 0; i < 4; ++i) {
            const int sb = sb0 + i;
            float wv[12];
            #pragma unroll
            for (int l = 0; l < 12; ++l) {
                int sw = sb - 11 + l; sw = sw < 0 ? 0 : sw;
                wv[l] = x[xbase + (size_t)sw * 64];
            }
            float sm = 0.f;
            #pragma unroll
            for (int l = 0; l < 12; ++l) sm += wv[l];
            float mean = sm * (1.f/12.f), sq = 0.f;
            #pragma unroll
            for (int l = 0; l < 12; ++l){ float d = wv[l]-mean; sq = fmaf(d,d,sq); }
            float sd  = sqrtf(sq * (1.f/12.f)) + 1e-8f;
            float inv = 1.f / (12.f * sd);        // fold 1/L sim scale into the window norm
            #pragma unroll
            for (int l = 0; l < 12; ++l) wv[l] = (wv[l]-mean)*inv;

            const int r = rg*4 + i;
            char* sbase = (char*)fl + ((r*1024 + 2*c) ^ ((r & 7) << 4));
            #pragma unroll
            for (int m = 0; m < 8; ++m) {
                const float4* mp = (const float4*)(mzf + (m*64 + c)*16);
                float4 m0 = mp[0], m1 = mp[1], m2 = mp[2];
                float dot = wv[0] * m0.x;
                dot = fmaf(wv[1],  m0.y, dot);
                dot = fmaf(wv[2],  m0.z, dot);
                dot = fmaf(wv[3],  m0.w, dot);
                dot = fmaf(wv[4],  m1.x, dot);
                dot = fmaf(wv[5],  m1.y, dot);
                dot = fmaf(wv[6],  m1.z, dot);
                dot = fmaf(wv[7],  m1.w, dot);
                dot = fmaf(wv[8],  m2.x, dot);
                dot = fmaf(wv[9],  m2.y, dot);
                dot = fmaf(wv[10], m2.z, dot);
                dot = fmaf(wv[11], m2.w, dot);
                float rv  = fmaxf(dot, 0.f);
                float rv2 = rv * rv;
                *(ushort*)(sbase + m*128) = f2bf(rv2*rv2);   // m*128 commutes with the XOR
            }
        }
    }

    // ---------------- GEMM1: [32x512]x[512x512], 2-named-buffer prefetch ----------------
    const ushort* ws1 = ws + W1S_OFF;
    bf16x8 p0[4], p1[4];
    #pragma unroll
    for (int tn = 0; tn < 4; ++tn) {
        p0[tn] = *(const bf16x8*)(ws1 + (size_t)((w*4 + tn)*16 + 0)*512 + lane*8);
        p1[tn] = *(const bf16x8*)(ws1 + (size_t)((w*4 + tn)*16 + 1)*512 + lane*8);
    }

    __syncthreads();

    f32x4 acc[2][4];
    #pragma unroll
    for (int mt = 0; mt < 2; ++mt)
        #pragma unroll
        for (int tn = 0; tn < 4; ++tn)
            acc[mt][tn] = (f32x4){0.f,0.f,0.f,0.f};

    #pragma unroll
    for (int th = 0; th < 8; ++th) {
        {
            const int tk = 2*th;
            bf16x8 a0[2];
            #pragma unroll
            for (int mt = 0; mt < 2; ++mt)
                a0[mt] = *(const bf16x8*)((char*)fl + SWZ(mt*16 + lo, tk*32 + hi*8));
            #pragma unroll
            for (int tn = 0; tn < 4; ++tn)
                #pragma unroll
                for (int mt = 0; mt < 2; ++mt)
                    acc[mt][tn] = __builtin_amdgcn_mfma_f32_16x16x32_bf16(a0[mt], p0[tn], acc[mt][tn], 0, 0, 0);
            if (th < 7) {
                #pragma unroll
                for (int tn = 0; tn < 4; ++tn)
                    p0[tn] = *(const bf16x8*)(ws1 + (size_t)((w*4 + tn)*16 + tk + 2)*512 + lane*8);
            }
        }
        {
            const int tk = 2*th + 1;
            bf16x8 a1[2];
            #pragma unroll
            for (int mt = 0; mt < 2; ++mt)
                a1[mt] = *(const bf16x8*)((char*)fl + SWZ(mt*16 + lo, tk*32 + hi*8));
            #pragma unroll
            for (int tn = 0; tn < 4; ++tn)
                #pragma unroll
                for (int mt = 0; mt < 2; ++mt)
                    acc[mt][tn] = __builtin_amdgcn_mfma_f32_16x16x32_bf16(a1[mt], p1[tn], acc[mt][tn], 0, 0, 0);
            if (th < 7) {
                #pragma unroll
                for (int tn = 0; tn < 4; ++tn)
                    p1[tn] = *(const bf16x8*)(ws1 + (size_t)((w*4 + tn)*16 + tk + 2)*512 + lane*8);
            }
        }
    }

    // ---------------- bias + fast gelu (in regs) ----------------
    {
        float b1v[4];
        #pragma unroll
        for (int tn = 0; tn < 4; ++tn) b1v[tn] = b1[n0 + tn*16 + lo];
        #pragma unroll
        for (int mt = 0; mt < 2; ++mt)
            #pragma unroll
            for (int tn = 0; tn < 4; ++tn)
                #pragma unroll
                for (int e = 0; e < 4; ++e)
                    acc[mt][tn][e] = fast_gelu(acc[mt][tn][e] + b1v[tn]);
    }

    // ---------------- LayerNorm: partials -> stats -> normalize -> hn bf16 LDS ----------------
    #pragma unroll
    for (int mt = 0; mt < 2; ++mt)
        #pragma unroll
        for (int e = 0; e < 4; ++e) {
            float s1 = 0.f, s2 = 0.f;
            #pragma unroll
            for (int tn = 0; tn < 4; ++tn) {
                float g = acc[mt][tn][e];
                s1 += g; s2 = fmaf(g, g, s2);
            }
            #pragma unroll
            for (int o = 1; o < 16; o <<= 1) {
                s1 += __shfl_xor(s1, o);
                s2 += __shfl_xor(s2, o);
            }
            if (lo == 0) {
                int row = mt*16 + hi*4 + e;
                part[row][w][0] = s1;
                part[row][w][1] = s2;
            }
        }
    __syncthreads();
    if (t < 32) {
        float s1 = 0.f, s2 = 0.f;
        #pragma unroll
        for (int ww = 0; ww < 8; ++ww) { s1 += part[t][ww][0]; s2 += part[t][ww][1]; }
        float mu  = s1 * (1.f/512.f);
        float var = s2 * (1.f/512.f) - mu*mu;
        mu_s[t] = mu;
        rs_s[t] = rsqrtf(var + 1e-5f);
    }
    __syncthreads();
    {
        float gv[4], bv[4];
        #pragma unroll
        for (int tn = 0; tn < 4; ++tn) {
            gv[tn] = gamma[n0 + tn*16 + lo];
            bv[tn] = beta[n0 + tn*16 + lo];
        }
        #pragma unroll
        for (int mt = 0; mt < 2; ++mt)
            #pragma unroll
            for (int e = 0; e < 4; ++e) {
                int row = mt*16 + hi*4 + e;
                float mu = mu_s[row], rs = rs_s[row];
                #pragma unroll
                for (int tn = 0; tn < 4; ++tn) {
                    float hn = (acc[mt][tn][e] - mu) * rs * gv[tn] + bv[tn];
                    int col = n0 + tn*16 + lo;
                    *(ushort*)((char*)fl + SWZ(row, col)) = f2bf(hn);
                }
            }
    }

    // ---------------- GEMM2: [32x512]x[512x256], 2-named-buffer prefetch ----------------
    const ushort* ws2 = ws + W2S_OFF;
    bf16x8 q0[2], q1[2];
    #pragma unroll
    for (int tn = 0; tn < 2; ++tn) {
        q0[tn] = *(const bf16x8*)(ws2 + (size_t)((w*2 + tn)*16 + 0)*512 + lane*8);
        q1[tn] = *(const bf16x8*)(ws2 + (size_t)((w*2 + tn)*16 + 1)*512 + lane*8);
    }

    __syncthreads();

    f32x4 acc2[2][2];
    #pragma unroll
    for (int mt = 0; mt < 2; ++mt)
        #pragma unroll
        for (int tn = 0; tn < 2; ++tn)
            acc2[mt][tn] = (f32x4){0.f,0.f,0.f,0.f};

    #pragma unroll
    for (int th = 0; th < 8; ++th) {
        {
            const int tk = 2*th;
            bf16x8 a0[2];
            #pragma unroll
            for (int mt = 0; mt < 2; ++mt)
                a0[mt] = *(const bf16x8*)((char*)fl + SWZ(mt*16 + lo, tk*32 + hi*8));
            #pragma unroll
            for (int tn = 0; tn < 2; ++tn)
                #pragma unroll
                for (int mt = 0; mt < 2; ++mt)
                    acc2[mt][tn] = __builtin_amdgcn_mfma_f32_16x16x32_bf16(a0[mt], q0[tn], acc2[mt][tn], 0, 0, 0);
            if (th < 7) {
                #pragma unroll
                for (int tn = 0; tn < 2; ++tn)
                    q0[tn] = *(const bf16x8*)(ws2 + (size_t)((w*2 + tn)*16 + tk + 2)*512 + lane*8);
            }
        }
        {
            const int tk = 2*th + 1;
            bf16x8 a1[2];
            #pragma unroll
            for (int mt = 0; mt < 2; ++mt)
                a1[mt] = *(const bf16x8*)((char*)fl + SWZ(mt*16 + lo, tk*32 + hi*8));
            #pragma unroll
            for (int tn = 0; tn < 2; ++tn)
                #pragma unroll
                for (int mt = 0; mt < 2; ++mt)
                    acc2[mt][tn] = __builtin_amdgcn_mfma_f32_16x16x32_bf16(a1[mt], q1[tn], acc2[mt][tn], 0, 0, 0);
            if (th < 7) {
                #pragma unroll
                for (int tn = 0; tn < 2; ++tn)
                    q1[tn] = *(const bf16x8*)(ws2 + (size_t)((w*2 + tn)*16 + tk + 2)*512 + lane*8);
            }
        }
    }

    // ---------------- + b2 -> swizzled fp32 LDS tile -> full-line stores ----------------
    __syncthreads();                              // all GEMM2 LDS reads retired
    {
        float* fl32 = (float*)fl;                 // [32][256] fp32, col4-XOR swizzled
        const int n2 = w * 32;
        float b2v[2];
        #pragma unroll
        for (int tn = 0; tn < 2; ++tn) b2v[tn] = b2[n2 + tn*16 + lo];
        #pragma unroll
        for (int mt = 0; mt < 2; ++mt)
            #pragma unroll
            for (int tn = 0; tn < 2; ++tn) {
                int col = n2 + tn*16 + lo;
                int c4 = col >> 2, ce = col & 3;
                #pragma unroll
                for (int e = 0; e < 4; ++e) {
                    int row = mt*16 + hi*4 + e;
                    fl32[row*256 + (((c4 ^ (row & 7)) << 2) | ce)] = acc2[mt][tn][e] + b2v[tn];
                }
            }
    }
    __syncthreads();
    {
        const float* fl32 = (const float*)fl;
        float4* dst = (float4*)out;
        const int row = t >> 4;                   // 0..31
        const int sg  = t & 15;                   // 0..15
        #pragma unroll
        for (int it = 0; it < 4; ++it) {
            int c4 = sg + it*16;
            float4 v = *(const float4*)&fl32[row*256 + ((c4 ^ (row & 7)) << 2)];
            dst[(size_t)(g0 + row)*64 + c4] = v;
        }
    }
}

extern "C" void kernel_launch(void* const* d_in, const int* in_sizes, int n_in,
                              void* d_out, int out_size, void* d_ws, size_t ws_size,
                              hipStream_t stream) {
    const float* x      = (const float*)d_in[0];
    const float* motifs = (const float*)d_in[1];
    const float* W1     = (const float*)d_in[2];
    const float* b1     = (const float*)d_in[3];
    const float* gamma  = (const float*)d_in[4];
    const float* beta   = (const float*)d_in[5];
    const float* W2     = (const float*)d_in[6];
    const float* b2     = (const float*)d_in[7];
    float* out = (float*)d_out;
    ushort* ws = (ushort*)d_ws;

    prep_kernel<<<(393216 + 512 + 255) / 256, 256, 0, stream>>>(W1, W2, motifs, ws);
    fused_kernel<<<1024, 512, 0, stream>>>(x, ws, b1, gamma, beta, b2, out);
}